// Round 2
// baseline (50.163 us; speedup 1.0000x reference)
//
#include <hip/hip_runtime.h>
#include <math.h>

using f32x4 = __attribute__((ext_vector_type(4))) float;

constexpr float TAU = 0.25f;
constexpr int T  = 16;
constexpr int NPT = 32 * 64 * 32 * 32;   // elements per timestep = 2,097,152
constexpr int HW  = 32 * 32;             // 1024 (divisible by 4 -> a float4 never crosses a channel)
constexpr int C   = 64;
constexpr int NV  = NPT / 4;             // float4 chunks per timestep = 524,288

__global__ __launch_bounds__(256) void lif_fwd(const float* __restrict__ x,
                                               const float* __restrict__ w,
                                               float* __restrict__ out) {
    const int i = blockIdx.x * blockDim.x + threadIdx.x;   // vec4 index in [0, NV)
    const int c = ((i * 4) / HW) % C;                      // channel (same for all 4 lanes of the vec)
    const float thre = (float)tanh((double)w[c]);          // correctly-rounded tanh -> float

    const f32x4* __restrict__ xv = reinterpret_cast<const f32x4*>(x);
    f32x4* __restrict__ ov       = reinterpret_cast<f32x4*>(out);

    // Preload all T timesteps: 16 independent global_load_dwordx4 in flight
    // per thread (64 VGPRs of payload) -> deep MLP, latency fully hidden.
    f32x4 xt[T];
#pragma unroll
    for (int t = 0; t < T; ++t) {
        xt[t] = xv[(size_t)t * NV + i];
    }

    f32x4 mem = 0.0f;
    f32x4 spk = 0.0f;

#pragma unroll
    for (int t = 0; t < T; ++t) {
        // TAU*mem is exact (x2^-2); (1-spk) is exactly 0 or 1; single rounding at +xt,
        // bit-identical to the numpy reference even under FMA contraction.
        f32x4 u = TAU * mem * (1.0f - spk) + xt[t];
        f32x4 o;
#pragma unroll
        for (int k = 0; k < 4; ++k) {
            o[k] = (u[k] - thre > 0.0f) ? 1.0f : 0.0f;
        }
        // Non-temporal store: stream spikes to HBM without allocating in L2/L3,
        // so the 128 MiB input x stays Infinity-Cache-resident across replays.
        __builtin_nontemporal_store(o, &ov[(size_t)t * NV + i]);
        mem = u;
        spk = o;
    }
}

extern "C" void kernel_launch(void* const* d_in, const int* in_sizes, int n_in,
                              void* d_out, int out_size, void* d_ws, size_t ws_size,
                              hipStream_t stream) {
    const float* x = (const float*)d_in[0];
    const float* w = (const float*)d_in[1];
    float* out = (float*)d_out;

    dim3 block(256);
    dim3 grid(NV / 256);   // 2048 blocks = 8 per CU
    lif_fwd<<<grid, block, 0, stream>>>(x, w, out);
}

// Round 3
// 46.094 us; speedup vs baseline: 1.0883x; 1.0883x over previous
//
#include <hip/hip_runtime.h>
#include <math.h>

using f32x4 = __attribute__((ext_vector_type(4))) float;

constexpr float TAU = 0.25f;
constexpr int T  = 16;
constexpr int NPT = 32 * 64 * 32 * 32;   // elements per timestep = 2,097,152
constexpr int HW  = 32 * 32;             // 1024
constexpr int C   = 64;
constexpr int NV  = NPT / 4;             // float4 chunks per timestep = 524,288
constexpr int VPT = 2;                   // vec4s per thread (adjacent -> 32B/lane bursts)
constexpr int NT  = NV / VPT;            // threads = 262,144

__global__ __launch_bounds__(256) void lif_fwd(const float* __restrict__ x,
                                               const float* __restrict__ w,
                                               float* __restrict__ out) {
    const int tid = blockIdx.x * blockDim.x + threadIdx.x;   // [0, NT)
    const int i0  = tid * VPT;                               // first vec4 index
    // 8 consecutive floats: HW=1024 divisible by 8 -> same channel for both vecs
    const int c = ((i0 * 4) / HW) % C;
    const float thre = (float)tanh((double)w[c]);

    const f32x4* __restrict__ xv = reinterpret_cast<const f32x4*>(x);
    f32x4* __restrict__ ov       = reinterpret_cast<f32x4*>(out);

    f32x4 mem0 = 0.0f, mem1 = 0.0f;
    f32x4 spk0 = 0.0f, spk1 = 0.0f;

#pragma unroll
    for (int t = 0; t < T; ++t) {
        const size_t base = (size_t)t * NV + i0;
        const f32x4 xt0 = xv[base];
        const f32x4 xt1 = xv[base + 1];
        // TAU*mem exact (x2^-2); (1-spk) exactly 0/1; single rounding at +xt:
        // bit-identical to the numpy reference even under FMA contraction.
        f32x4 u0 = TAU * mem0 * (1.0f - spk0) + xt0;
        f32x4 u1 = TAU * mem1 * (1.0f - spk1) + xt1;
        f32x4 o0, o1;
#pragma unroll
        for (int k = 0; k < 4; ++k) {
            o0[k] = (u0[k] - thre > 0.0f) ? 1.0f : 0.0f;
            o1[k] = (u1[k] - thre > 0.0f) ? 1.0f : 0.0f;
        }
        ov[base]     = o0;
        ov[base + 1] = o1;
        mem0 = u0; spk0 = o0;
        mem1 = u1; spk1 = o1;
    }
}

extern "C" void kernel_launch(void* const* d_in, const int* in_sizes, int n_in,
                              void* d_out, int out_size, void* d_ws, size_t ws_size,
                              hipStream_t stream) {
    const float* x = (const float*)d_in[0];
    const float* w = (const float*)d_in[1];
    float* out = (float*)d_out;

    dim3 block(256);
    dim3 grid(NT / 256);   // 1024 blocks = 4 per CU
    lif_fwd<<<grid, block, 0, stream>>>(x, w, out);
}